// Round 16
// baseline (43.426 us; speedup 1.0000x reference)
//
#include <hip/hip_runtime.h>
#include <math.h>

#define CDIM 128
#define HW   4096
#define HEADS 4
#define HD   32

typedef __attribute__((ext_vector_type(8))) short bf16x8;
typedef __attribute__((ext_vector_type(4))) float f32x4;

static __device__ __forceinline__ unsigned int f2bf(float f) {
  union { float f; unsigned int u; } v; v.f = f;
  unsigned int r = v.u + 0x7FFF + ((v.u >> 16) & 1);   // RNE
  return r >> 16;
}
static __device__ __forceinline__ float bflo(unsigned int u) {
  return __uint_as_float(u << 16);
}
static __device__ __forceinline__ float bfhi(unsigned int u) {
  return __uint_as_float(u & 0xFFFF0000u);
}
// tanh-form gelu via sigmoid; |err| vs exact < ~1e-3 (validated R8/R11)
static __device__ __forceinline__ float gelu_f(float v) {
  float y = v * (1.595769122f + 0.071354816f * v * v);
  return v / (1.0f + __expf(-y));
}

// ================= head v3: rmsnorm + qkv GEMM; sel=1 does k AND v (h read once) =====
// grid (128, 3), block 256. sel 0: q from z. sel 1: k+v from h. sel 2: cvt wo/w1/w2.
__global__ __launch_bounds__(256) void head(
    const float* __restrict__ z, const float* __restrict__ h,
    const float* __restrict__ wzn, const float* __restrict__ whn,
    const float* __restrict__ wq, const float* __restrict__ bq,
    const float* __restrict__ wk, const float* __restrict__ bk,
    const float* __restrict__ wv, const float* __restrict__ bv,
    const float* __restrict__ wo, const float* __restrict__ w1,
    const float* __restrict__ w2, ushort* __restrict__ WB,
    ushort* __restrict__ Qb, ushort* __restrict__ Kb, ushort* __restrict__ Vb) {
  const int sel = blockIdx.y, t = threadIdx.x;
  if (sel == 2) {
    // convert wo (16384) | w1 (32768) | w2 (32768) into WB+49152 (80 active blocks)
    int e = (blockIdx.x * 256 + t) * 4;
    if (e < 81920) {
      const float* src; int off;
      if      (e < 16384) { src = wo; off = 0; }
      else if (e < 49152) { src = w1; off = 16384; }
      else                { src = w2; off = 49152; }
      float4 v = *(const float4*)&src[e - off];
      uint2 r;
      r.x = f2bf(v.x) | (f2bf(v.y) << 16);
      r.y = f2bf(v.z) | (f2bf(v.w) << 16);
      *(uint2*)&WB[49152 + e] = r;
    }
    return;
  }
  __shared__ __align__(16) ushort sW[128 * 128];   // [out][k] bf16, XOR-swizzled
  __shared__ __align__(16) ushort sX[64 * 128];    // [px][ch] bf16, XOR-swizzled
  __shared__ float sh[4][64];

  const float* X  = (sel == 0) ? z : h;
  const float* wn = (sel == 0) ? wzn : whn;

  // ---- stage W fp32 -> bf16 LDS (swizzled rows); reused for the v-pass ----
  auto stage_w = [&](const float* __restrict__ Wf) {
#pragma unroll
    for (int i = 0; i < 8; ++i) {
      int u  = t + i * 256;                  // 2048 chunks of 8 elems
      int o  = u >> 4;
      int k8 = (u & 15) * 8;
      float4 v0 = *(const float4*)&Wf[o * 128 + k8];
      float4 v1 = *(const float4*)&Wf[o * 128 + k8 + 4];
      uint4 pk;
      pk.x = f2bf(v0.x) | (f2bf(v0.y) << 16);
      pk.y = f2bf(v0.z) | (f2bf(v0.w) << 16);
      pk.z = f2bf(v1.x) | (f2bf(v1.y) << 16);
      pk.w = f2bf(v1.z) | (f2bf(v1.w) << 16);
      int idx = (o * 128 + k8) ^ ((o & 7) << 3);
      *(uint4*)&sW[idx] = pk;
    }
  };
  stage_w((sel == 0) ? wq : wk);

  // ---- rmsnorm 64 pixels -> sX bf16 [px][ch] swizzled (once per block) ----
  const int pl = t & 63, g = t >> 6;
  const int gp = blockIdx.x * 64 + pl;     // global pixel (b*4096 + p)
  const size_t xbase = (size_t)(gp >> 12) * CDIM * HW + (gp & 4095);
  float vals[32];
  float ss = 0.f;
#pragma unroll
  for (int j = 0; j < 32; ++j) {
    float v = X[xbase + (size_t)(g * 32 + j) * HW];
    vals[j] = v;
    ss += v * v;
  }
  sh[g][pl] = ss;
  __syncthreads();
  float tot = sh[0][pl] + sh[1][pl] + sh[2][pl] + sh[3][pl];
  float inv = rsqrtf(tot * (1.0f / CDIM) + 1e-8f);
#pragma unroll
  for (int jj = 0; jj < 4; ++jj) {
    unsigned int u[4];
#pragma unroll
    for (int p2 = 0; p2 < 4; ++p2) {
      int j = jj * 8 + p2 * 2;
      float a = vals[j]     * inv * wn[g * 32 + j];
      float b = vals[j + 1] * inv * wn[g * 32 + j + 1];
      u[p2] = f2bf(a) | (f2bf(b) << 16);
    }
    int idx = (pl * 128 + g * 32 + jj * 8) ^ ((pl & 7) << 3);
    *(uint4*)&sX[idx] = make_uint4(u[0], u[1], u[2], u[3]);
  }
  __syncthreads();

  // ---- B-frags into regs (held across both passes) ----
  const int w = t >> 6, l = t & 63, lr = l & 15, lk = l >> 4;
  const int m0 = w * 32;
  const int swz = (lr & 7) << 3;           // (row&7)<<3 with row%8 == lr%8 everywhere
  bf16x8 bfr[4][4];                        // [k0/32][nf]
#pragma unroll
  for (int ki = 0; ki < 4; ++ki)
#pragma unroll
    for (int nf = 0; nf < 4; ++nf)
      bfr[ki][nf] = *(const bf16x8*)&sX[((nf * 16 + lr) * 128 + ki * 32 + lk * 8) ^ swz];

  // ---- GEMM from sW (LDS) x bfr (regs); epilogue packs bf16 [P][c] ----
  auto do_gemm = [&](const float* __restrict__ bias, ushort* __restrict__ outB) {
    f32x4 acc[2][4] = {};
#pragma unroll
    for (int ki = 0; ki < 4; ++ki) {
      int k0 = ki * 32;
      bf16x8 a0 = *(const bf16x8*)&sW[((m0 + lr) * 128 + k0 + lk * 8) ^ swz];
      bf16x8 a1 = *(const bf16x8*)&sW[((m0 + 16 + lr) * 128 + k0 + lk * 8) ^ swz];
#pragma unroll
      for (int nf = 0; nf < 4; ++nf) {
        acc[0][nf] = __builtin_amdgcn_mfma_f32_16x16x32_bf16(a0, bfr[ki][nf], acc[0][nf], 0, 0, 0);
        acc[1][nf] = __builtin_amdgcn_mfma_f32_16x16x32_bf16(a1, bfr[ki][nf], acc[1][nf], 0, 0, 0);
      }
    }
#pragma unroll
    for (int mf = 0; mf < 2; ++mf) {
      int obase = m0 + mf * 16 + lk * 4;
      f32x4 bv4 = *(const f32x4*)&bias[obase];
#pragma unroll
      for (int nf = 0; nf < 4; ++nf) {
        int P = blockIdx.x * 64 + nf * 16 + lr;
        uint2 pk;
        pk.x = f2bf(acc[mf][nf][0] + bv4[0]) | (f2bf(acc[mf][nf][1] + bv4[1]) << 16);
        pk.y = f2bf(acc[mf][nf][2] + bv4[2]) | (f2bf(acc[mf][nf][3] + bv4[3]) << 16);
        *(uint2*)&outB[(size_t)P * CDIM + obase] = pk;
      }
    }
  };

  do_gemm((sel == 0) ? bq : bk, (sel == 0) ? Qb : Kb);
  if (sel == 1) {                          // v-pass: re-stage sW only (sX/bfr reused)
    __syncthreads();                       // all sW reads of k-pass complete
    stage_w(wv);
    __syncthreads();
    do_gemm(bv, Vb);
  }
}

// ================= neighborhood attention (R11 verbatim) =========
// Block = (2 rows, head, batch): 512 thr = 128 px * 4 d-groups. LDS 80 KiB.
__global__ __launch_bounds__(512) void nattn(
    const ushort* __restrict__ Q, const ushort* __restrict__ K,
    const ushort* __restrict__ V, ushort* __restrict__ ATT) {
  __shared__ __align__(16) unsigned int smem[20480];   // 80 KiB
  float* sS = (float*)smem;
  const int t  = threadIdx.x;
  const int px = t & 127;
  const int x  = px & 63;
  const int r  = px >> 6;
  const int dg = t >> 7;          // 0..3
  const int y0 = blockIdx.x * 2;
  const int h  = blockIdx.y;
  const int b  = blockIdx.z;
  const int ybase = y0 - 3;

  {
    int yy = t >> 6, xs = t & 63;
    int gy = min(max(ybase + yy, 0), 63);
    size_t gb = ((size_t)(b * HW + gy * 64 + xs)) * 64 + h * 16;   // uint units
    const unsigned int* Ku = (const unsigned int*)K;
    const unsigned int* Vu = (const unsigned int*)V;
    int lb = (yy * 64 + xs) * 20;
#pragma unroll
    for (int i = 0; i < 4; ++i) {
      uint4 kv = *(const uint4*)&Ku[gb + i * 4];
      uint4 vv = *(const uint4*)&Vu[gb + i * 4];
      *(uint4*)&smem[lb + i * 4]         = kv;
      *(uint4*)&smem[10240 + lb + i * 4] = vv;
    }
  }
  const int Pq = b * HW + (y0 + r) * 64 + x;
  const unsigned int* Qu = (const unsigned int*)Q;
  float q[32];
#pragma unroll
  for (int i = 0; i < 4; ++i) {
    uint4 u4 = *(const uint4*)&Qu[(size_t)Pq * 64 + h * 16 + i * 4];
    q[i*8+0] = bflo(u4.x); q[i*8+1] = bfhi(u4.x);
    q[i*8+2] = bflo(u4.y); q[i*8+3] = bfhi(u4.y);
    q[i*8+4] = bflo(u4.z); q[i*8+5] = bfhi(u4.z);
    q[i*8+6] = bflo(u4.w); q[i*8+7] = bfhi(u4.w);
  }
  __syncthreads();

  const float scale = 0.17677669529663687f;  // 32^-0.5
  const int nb0    = (dg == 0) ? 0 : dg * 12 + 1;
  const int ncount = (dg == 0) ? 13 : 12;
  float sreg[13];
#pragma unroll
  for (int j = 0; j < 13; ++j) {
    if (j < ncount) {
      int nb = nb0 + j;
      int dy = nb / 7 - 3;
      int dx = nb % 7 - 3;
      int ry = r + dy + 3;
      int nx = x + dx;
      int xx = min(max(nx, 0), 63);
      int ny = y0 + r + dy;
      bool valid = (ny >= 0) && (ny <= 63) && (nx >= 0) && (nx <= 63);
      const unsigned int* kb = &smem[(ry * 64 + xx) * 20];
      float acc = 0.f;
#pragma unroll
      for (int c = 0; c < 4; ++c) {
        uint4 u4 = *(const uint4*)&kb[c * 4];
        acc += q[c*8+0] * bflo(u4.x) + q[c*8+1] * bfhi(u4.x);
        acc += q[c*8+2] * bflo(u4.y) + q[c*8+3] * bfhi(u4.y);
        acc += q[c*8+4] * bflo(u4.z) + q[c*8+5] * bfhi(u4.z);
        acc += q[c*8+6] * bflo(u4.w) + q[c*8+7] * bfhi(u4.w);
      }
      sreg[j] = valid ? __expf(acc * scale - 8.0f) : 0.0f;   // |s|<<8 -> overflow-safe
    }
  }
  __syncthreads();                   // all K reads done before sS overlay
#pragma unroll
  for (int j = 0; j < 13; ++j)
    if (j < ncount) sS[(nb0 + j) * 128 + px] = sreg[j];
  __syncthreads();

  float o[8] = {0.f, 0.f, 0.f, 0.f, 0.f, 0.f, 0.f, 0.f};
  float sum = 0.f;
#pragma unroll
  for (int nb = 0; nb < 49; ++nb) {
    float p = sS[nb * 128 + px];
    sum += p;
    int ry = r + nb / 7;                          // nb static
    int xx = min(max(x + nb % 7 - 3, 0), 63);
    uint4 u4 = *(const uint4*)&smem[10240 + (ry * 64 + xx) * 20 + dg * 4];
    o[0] += p * bflo(u4.x); o[1] += p * bfhi(u4.x);
    o[2] += p * bflo(u4.y); o[3] += p * bfhi(u4.y);
    o[4] += p * bflo(u4.z); o[5] += p * bfhi(u4.z);
    o[6] += p * bflo(u4.w); o[7] += p * bfhi(u4.w);
  }
  float inv = 1.0f / sum;
  unsigned int pk[4];
#pragma unroll
  for (int j = 0; j < 4; ++j)
    pk[j] = f2bf(o[2*j] * inv) | (f2bf(o[2*j+1] * inv) << 16);
  *(uint4*)&ATT[(size_t)Pq * CDIM + h * HD + dg * 8] = make_uint4(pk[0], pk[1], pk[2], pk[3]);
}

// ================= tail (R11 verbatim): 32 px, 256 thr, grid 256 ======
__global__ __launch_bounds__(256) void tail(
    const ushort* __restrict__ ATT, const ushort* __restrict__ WB,
    const float* __restrict__ bo, const float* __restrict__ z,
    const float* __restrict__ wfn, const float* __restrict__ b1,
    const float* __restrict__ b2, float* __restrict__ out) {
  __shared__ __align__(16) float  zlds[32][132];    // fp32 ZNEW tile
  __shared__ __align__(16) ushort fn_s[32 * 128];   // bf16 FN, XOR-swizzled
  __shared__ __align__(16) ushort hid_s[32 * 256];  // bf16 hidden, XOR-swizzled
  __shared__ float sums[32][17];
  __shared__ float sinv[32];
  const ushort* Wo = WB + 49152;
  const ushort* W1 = WB + 65536;
  const ushort* W2 = WB + 98304;
  const int t = threadIdx.x, w = t >> 6, l = t & 63, lr = l & 15, lk = l >> 4;
  const int pblk = blockIdx.x * 32;
  const int m0 = w * 32;

  // ---- phase A: wo GEMM (K=128), 4 waves x (32 out x 32 px) ----
  {
    const ushort* A0 = Wo + (size_t)(m0 + lr) * 128 + lk * 8;
    const ushort* A1 = A0 + 16 * 128;
    const ushort* B0 = ATT + (size_t)(pblk + lr) * 128 + lk * 8;
    const ushort* B1 = B0 + 16 * 128;
    f32x4 acc[2][2] = {};
#pragma unroll
    for (int k0 = 0; k0 < 128; k0 += 32) {
      bf16x8 a0 = *(const bf16x8*)(A0 + k0);
      bf16x8 a1 = *(const bf16x8*)(A1 + k0);
      bf16x8 b0 = *(const bf16x8*)(B0 + k0);
      bf16x8 b1 = *(const bf16x8*)(B1 + k0);
      acc[0][0] = __builtin_amdgcn_mfma_f32_16x16x32_bf16(a0, b0, acc[0][0], 0, 0, 0);
      acc[0][1] = __builtin_amdgcn_mfma_f32_16x16x32_bf16(a0, b1, acc[0][1], 0, 0, 0);
      acc[1][0] = __builtin_amdgcn_mfma_f32_16x16x32_bf16(a1, b0, acc[1][0], 0, 0, 0);
      acc[1][1] = __builtin_amdgcn_mfma_f32_16x16x32_bf16(a1, b1, acc[1][1], 0, 0, 0);
    }
#pragma unroll
    for (int nf = 0; nf < 2; ++nf) {
      int px = nf * 16 + lr;
      int P  = pblk + px;
      int b_ = P >> 12, p = P & 4095;
      float ss = 0.f;
#pragma unroll
      for (int mf = 0; mf < 2; ++mf) {
        int row0 = m0 + mf * 16 + lk * 4;
        f32x4 bv = *(const f32x4*)&bo[row0];
        f32x4 rr;
#pragma unroll
        for (int j = 0; j < 4; ++j) {
          size_t gi = ((size_t)(b_ * CDIM + row0 + j)) * HW + p;
          float u = acc[mf][nf][j] + bv[j] + z[gi];
          rr[j] = u;
          ss += u * u;
        }
        *(f32x4*)&zlds[px][row0] = rr;
      }
      sums[px][w * 4 + lk] = ss;
    }
  }
  __syncthreads();
  if (t < 32) {
    float tot = 0.f;
#pragma unroll
    for (int i = 0; i < 16; ++i) tot += sums[t][i];
    sinv[t] = rsqrtf(tot * (1.0f / CDIM) + 1e-8f);
  }
  __syncthreads();
  // ---- FN = rmsnorm(ZNEW)*wfn -> fn_s ----
#pragma unroll
  for (int nf = 0; nf < 2; ++nf) {
    int px = nf * 16 + lr;
    float inv = sinv[px];
#pragma unroll
    for (int mf = 0; mf < 2; ++mf) {
      int row0 = m0 + mf * 16 + lk * 4;
      f32x4 uu = *(const f32x4*)&zlds[px][row0];
      f32x4 wf = *(const f32x4*)&wfn[row0];
      uint2 pk;
      pk.x = f2bf(uu[0] * inv * wf[0]) | (f2bf(uu[1] * inv * wf[1]) << 16);
      pk.y = f2bf(uu[2] * inv * wf[2]) | (f2bf(uu[3] * inv * wf[3]) << 16);
      int idx = (px * 128 + row0) ^ ((px & 7) << 3);
      *(uint2*)&fn_s[idx] = pk;
    }
  }
  __syncthreads();
  // ---- phase B: ffn1 (K=128), 4 waves x (64 hid x 32 px); gelu -> hid_s ----
  {
    const int hm0 = w * 64;
    const ushort* A0 = W1 + (size_t)(hm0 + lr) * 128 + lk * 8;
    f32x4 acc1[4][2] = {};
#pragma unroll
    for (int k0 = 0; k0 < 128; k0 += 32) {
      bf16x8 a[4], b[2];
#pragma unroll
      for (int mf = 0; mf < 4; ++mf) a[mf] = *(const bf16x8*)(A0 + mf * 16 * 128 + k0);
#pragma unroll
      for (int nf = 0; nf < 2; ++nf) {
        int px = nf * 16 + lr;
        b[nf] = *(const bf16x8*)&fn_s[(px * 128 + k0 + lk * 8) ^ ((px & 7) << 3)];
      }
#pragma unroll
      for (int mf = 0; mf < 4; ++mf)
#pragma unroll
        for (int nf = 0; nf < 2; ++nf)
          acc1[mf][nf] = __builtin_amdgcn_mfma_f32_16x16x32_bf16(a[mf], b[nf], acc1[mf][nf], 0, 0, 0);
    }
#pragma unroll
    for (int mf = 0; mf < 4; ++mf) {
      int ch0 = hm0 + mf * 16 + lk * 4;
      f32x4 bv = *(const f32x4*)&b1[ch0];
#pragma unroll
      for (int nf = 0; nf < 2; ++nf) {
        int px = nf * 16 + lr;
        float v0 = gelu_f(acc1[mf][nf][0] + bv[0]);
        float v1 = gelu_f(acc1[mf][nf][1] + bv[1]);
        float v2 = gelu_f(acc1[mf][nf][2] + bv[2]);
        float v3 = gelu_f(acc1[mf][nf][3] + bv[3]);
        uint2 pk;
        pk.x = f2bf(v0) | (f2bf(v1) << 16);
        pk.y = f2bf(v2) | (f2bf(v3) << 16);
        int idx = (px * 256 + ch0) ^ ((px & 7) << 3);
        *(uint2*)&hid_s[idx] = pk;
      }
    }
  }
  __syncthreads();
  // ---- phase C: ffn2 (K=256), 4 waves x (32 out x 32 px); +b2 +ZNEW -> out ----
  {
    const ushort* C0 = W2 + (size_t)(m0 + lr) * 256 + lk * 8;
    f32x4 acc2[2][2] = {};
#pragma unroll
    for (int k0 = 0; k0 < 256; k0 += 32) {
      bf16x8 a0 = *(const bf16x8*)(C0 + k0);
      bf16x8 a1 = *(const bf16x8*)(C0 + 16 * 256 + k0);
      bf16x8 b[2];
#pragma unroll
      for (int nf = 0; nf < 2; ++nf) {
        int px = nf * 16 + lr;
        b[nf] = *(const bf16x8*)&hid_s[(px * 256 + k0 + lk * 8) ^ ((px & 7) << 3)];
      }
      acc2[0][0] = __builtin_amdgcn_mfma_f32_16x16x32_bf16(a0, b[0], acc2[0][0], 0, 0, 0);
      acc2[0][1] = __builtin_amdgcn_mfma_f32_16x16x32_bf16(a0, b[1], acc2[0][1], 0, 0, 0);
      acc2[1][0] = __builtin_amdgcn_mfma_f32_16x16x32_bf16(a1, b[0], acc2[1][0], 0, 0, 0);
      acc2[1][1] = __builtin_amdgcn_mfma_f32_16x16x32_bf16(a1, b[1], acc2[1][1], 0, 0, 0);
    }
#pragma unroll
    for (int mf = 0; mf < 2; ++mf) {
      int row0 = m0 + mf * 16 + lk * 4;
      f32x4 bv = *(const f32x4*)&b2[row0];
#pragma unroll
      for (int nf = 0; nf < 2; ++nf) {
        int px = nf * 16 + lr;
        int P  = pblk + px;
        int b_ = P >> 12, p = P & 4095;
        f32x4 zz = *(const f32x4*)&zlds[px][row0];
#pragma unroll
        for (int j = 0; j < 4; ++j) {
          size_t gi = ((size_t)(b_ * CDIM + row0 + j)) * HW + p;
          out[gi] = acc2[mf][nf][j] + bv[j] + zz[j];
        }
      }
    }
  }
}

// ================= launch =================
extern "C" void kernel_launch(void* const* d_in, const int* in_sizes, int n_in,
                              void* d_out, int out_size, void* d_ws, size_t ws_size,
                              hipStream_t stream) {
  const float* z   = (const float*)d_in[0];
  const float* h   = (const float*)d_in[1];
  const float* wzn = (const float*)d_in[2];
  const float* whn = (const float*)d_in[3];
  const float* wq  = (const float*)d_in[4];
  const float* bq  = (const float*)d_in[5];
  const float* wk  = (const float*)d_in[6];
  const float* bk  = (const float*)d_in[7];
  const float* wv  = (const float*)d_in[8];
  const float* bv  = (const float*)d_in[9];
  const float* wo  = (const float*)d_in[10];
  const float* bo  = (const float*)d_in[11];
  const float* wfn = (const float*)d_in[12];
  const float* w1  = (const float*)d_in[13];
  const float* b1  = (const float*)d_in[14];
  const float* w2  = (const float*)d_in[15];
  const float* b2  = (const float*)d_in[16];
  float* out = (float*)d_out;

  const size_t U = 1048576;                  // one [8192][128] bf16 tensor (ushorts)
  ushort* Qb  = (ushort*)d_ws;
  ushort* Kb  = Qb + U;
  ushort* Vb  = Kb + U;
  ushort* ATT = Vb + U;
  ushort* WB  = ATT + U;                     // 131072 ushorts (wo/w1/w2 at +49152)

  head<<<dim3(128, 3), 256, 0, stream>>>(z, h, wzn, whn, wq, bq, wk, bk, wv, bv,
                                         wo, w1, w2, WB, Qb, Kb, Vb);
  nattn<<<dim3(32, HEADS, 2), 512, 0, stream>>>(Qb, Kb, Vb, ATT);
  tail<<<dim3(256), 256, 0, stream>>>(ATT, WB, bo, z, wfn, b1, b2, out);
}

// Round 17
// 38.435 us; speedup vs baseline: 1.1298x; 1.1298x over previous
//
#include <hip/hip_runtime.h>
#include <math.h>

#define CDIM 128
#define HW   4096
#define HEADS 4
#define HD   32

typedef __attribute__((ext_vector_type(8))) short bf16x8;
typedef __attribute__((ext_vector_type(4))) float f32x4;

static __device__ __forceinline__ unsigned int f2bf(float f) {
  union { float f; unsigned int u; } v; v.f = f;
  unsigned int r = v.u + 0x7FFF + ((v.u >> 16) & 1);   // RNE
  return r >> 16;
}
static __device__ __forceinline__ float bflo(unsigned int u) {
  return __uint_as_float(u << 16);
}
static __device__ __forceinline__ float bfhi(unsigned int u) {
  return __uint_as_float(u & 0xFFFF0000u);
}
// tanh-form gelu via sigmoid; |err| vs exact < ~1e-3 (validated R8/R11)
static __device__ __forceinline__ float gelu_f(float v) {
  float y = v * (1.595769122f + 0.071354816f * v * v);
  return v / (1.0f + __expf(-y));
}

// ================= head: rmsnorm + qkv GEMM fused; y==3 slice converts tail weights =====
// grid (128, 4), block 256. y=0: q from z; y=1: k from h; y=2: v from h.
__global__ __launch_bounds__(256) void head(
    const float* __restrict__ z, const float* __restrict__ h,
    const float* __restrict__ wzn, const float* __restrict__ whn,
    const float* __restrict__ wq, const float* __restrict__ bq,
    const float* __restrict__ wk, const float* __restrict__ bk,
    const float* __restrict__ wv, const float* __restrict__ bv,
    const float* __restrict__ wo, const float* __restrict__ w1,
    const float* __restrict__ w2, ushort* __restrict__ WB,
    ushort* __restrict__ Qb, ushort* __restrict__ Kb, ushort* __restrict__ Vb) {
  const int sel = blockIdx.y, t = threadIdx.x;
  if (sel == 3) {
    int e = (blockIdx.x * 256 + t) * 4;
    if (e < 81920) {
      const float* src; int off;
      if      (e < 16384) { src = wo; off = 0; }
      else if (e < 49152) { src = w1; off = 16384; }
      else                { src = w2; off = 49152; }
      float4 v = *(const float4*)&src[e - off];
      uint2 r;
      r.x = f2bf(v.x) | (f2bf(v.y) << 16);
      r.y = f2bf(v.z) | (f2bf(v.w) << 16);
      *(uint2*)&WB[49152 + e] = r;
    }
    return;
  }
  __shared__ __align__(16) ushort sW[128 * 128];   // [out][k] bf16, XOR-swizzled
  __shared__ __align__(16) ushort sX[64 * 128];    // [px][ch] bf16, XOR-swizzled
  __shared__ float sh[4][64];

  const float* X    = (sel == 0) ? z : h;
  const float* wn   = (sel == 0) ? wzn : whn;
  const float* Wf   = (sel == 0) ? wq : (sel == 1 ? wk : wv);
  const float* bias = (sel == 0) ? bq : (sel == 1 ? bk : bv);
  ushort* outB      = (sel == 0) ? Qb : (sel == 1 ? Kb : Vb);

  // ---- stage W: fp32 global -> bf16 LDS (swizzled rows) ----
#pragma unroll
  for (int i = 0; i < 8; ++i) {
    int u  = t + i * 256;                  // 2048 chunks of 8 elems
    int o  = u >> 4;
    int k8 = (u & 15) * 8;
    float4 v0 = *(const float4*)&Wf[o * 128 + k8];
    float4 v1 = *(const float4*)&Wf[o * 128 + k8 + 4];
    uint4 pk;
    pk.x = f2bf(v0.x) | (f2bf(v0.y) << 16);
    pk.y = f2bf(v0.z) | (f2bf(v0.w) << 16);
    pk.z = f2bf(v1.x) | (f2bf(v1.y) << 16);
    pk.w = f2bf(v1.z) | (f2bf(v1.w) << 16);
    int idx = (o * 128 + k8) ^ ((o & 7) << 3);
    *(uint4*)&sW[idx] = pk;
  }

  // ---- rmsnorm 64 pixels -> sX bf16 [px][ch] swizzled ----
  const int pl = t & 63, g = t >> 6;
  const int gp = blockIdx.x * 64 + pl;     // global pixel (b*4096 + p)
  const size_t xbase = (size_t)(gp >> 12) * CDIM * HW + (gp & 4095);
  float vals[32];
  float ss = 0.f;
#pragma unroll
  for (int j = 0; j < 32; ++j) {
    float v = X[xbase + (size_t)(g * 32 + j) * HW];
    vals[j] = v;
    ss += v * v;
  }
  sh[g][pl] = ss;
  __syncthreads();
  float tot = sh[0][pl] + sh[1][pl] + sh[2][pl] + sh[3][pl];
  float inv = rsqrtf(tot * (1.0f / CDIM) + 1e-8f);
#pragma unroll
  for (int jj = 0; jj < 4; ++jj) {
    unsigned int u[4];
#pragma unroll
    for (int p2 = 0; p2 < 4; ++p2) {
      int j = jj * 8 + p2 * 2;
      float a = vals[j]     * inv * wn[g * 32 + j];
      float b = vals[j + 1] * inv * wn[g * 32 + j + 1];
      u[p2] = f2bf(a) | (f2bf(b) << 16);
    }
    int idx = (pl * 128 + g * 32 + jj * 8) ^ ((pl & 7) << 3);
    *(uint4*)&sX[idx] = make_uint4(u[0], u[1], u[2], u[3]);
  }
  __syncthreads();

  // ---- MFMA: wave w -> 32 Cout x 64 px ----
  const int w = t >> 6, l = t & 63, lr = l & 15, lk = l >> 4;
  const int m0 = w * 32;
  const int swz = (lr & 7) << 3;           // (row&7)<<3 with row%8 == lr%8 everywhere
  f32x4 acc[2][4] = {};
#pragma unroll
  for (int k0 = 0; k0 < 128; k0 += 32) {
    bf16x8 a0 = *(const bf16x8*)&sW[((m0 + lr) * 128 + k0 + lk * 8) ^ swz];
    bf16x8 a1 = *(const bf16x8*)&sW[((m0 + 16 + lr) * 128 + k0 + lk * 8) ^ swz];
    bf16x8 b[4];
#pragma unroll
    for (int nf = 0; nf < 4; ++nf)
      b[nf] = *(const bf16x8*)&sX[((nf * 16 + lr) * 128 + k0 + lk * 8) ^ swz];
#pragma unroll
    for (int nf = 0; nf < 4; ++nf) {
      acc[0][nf] = __builtin_amdgcn_mfma_f32_16x16x32_bf16(a0, b[nf], acc[0][nf], 0, 0, 0);
      acc[1][nf] = __builtin_amdgcn_mfma_f32_16x16x32_bf16(a1, b[nf], acc[1][nf], 0, 0, 0);
    }
  }
#pragma unroll
  for (int mf = 0; mf < 2; ++mf) {
    int obase = m0 + mf * 16 + lk * 4;
    f32x4 bv = *(const f32x4*)&bias[obase];
#pragma unroll
    for (int nf = 0; nf < 4; ++nf) {
      int P = blockIdx.x * 64 + nf * 16 + lr;
      uint2 pk;
      pk.x = f2bf(acc[mf][nf][0] + bv[0]) | (f2bf(acc[mf][nf][1] + bv[1]) << 16);
      pk.y = f2bf(acc[mf][nf][2] + bv[2]) | (f2bf(acc[mf][nf][3] + bv[3]) << 16);
      *(uint2*)&outB[(size_t)P * CDIM + obase] = pk;
    }
  }
}

// ================= neighborhood attention: per-pixel-packed LDS, p stored in sS =========
// Block = (2 rows, head, batch): 512 thr = 128 px * 4 d-groups. LDS 80 KiB.
// K at [yy][x][20 uints] (16 data + 4 pad), V same at +10240. sS[49][128] f32 aliases K.
__global__ __launch_bounds__(512) void nattn(
    const ushort* __restrict__ Q, const ushort* __restrict__ K,
    const ushort* __restrict__ V, ushort* __restrict__ ATT) {
  __shared__ __align__(16) unsigned int smem[20480];   // 80 KiB
  float* sS = (float*)smem;
  const int t  = threadIdx.x;
  const int px = t & 127;
  const int x  = px & 63;
  const int r  = px >> 6;
  const int dg = t >> 7;          // 0..3
  const int y0 = blockIdx.x * 2;
  const int h  = blockIdx.y;
  const int b  = blockIdx.z;
  const int ybase = y0 - 3;

  // ---- stage: one halo pixel per thread; 16+16 packed uints, b128 writes ----
  {
    int yy = t >> 6, xs = t & 63;
    int gy = min(max(ybase + yy, 0), 63);
    size_t gb = ((size_t)(b * HW + gy * 64 + xs)) * 64 + h * 16;   // uint units
    const unsigned int* Ku = (const unsigned int*)K;
    const unsigned int* Vu = (const unsigned int*)V;
    int lb = (yy * 64 + xs) * 20;
#pragma unroll
    for (int i = 0; i < 4; ++i) {
      uint4 kv = *(const uint4*)&Ku[gb + i * 4];
      uint4 vv = *(const uint4*)&Vu[gb + i * 4];
      *(uint4*)&smem[lb + i * 4]         = kv;
      *(uint4*)&smem[10240 + lb + i * 4] = vv;
    }
  }
  // ---- q into regs ----
  const int Pq = b * HW + (y0 + r) * 64 + x;
  const unsigned int* Qu = (const unsigned int*)Q;
  float q[32];
#pragma unroll
  for (int i = 0; i < 4; ++i) {
    uint4 u4 = *(const uint4*)&Qu[(size_t)Pq * 64 + h * 16 + i * 4];
    q[i*8+0] = bflo(u4.x); q[i*8+1] = bfhi(u4.x);
    q[i*8+2] = bflo(u4.y); q[i*8+3] = bfhi(u4.y);
    q[i*8+4] = bflo(u4.z); q[i*8+5] = bfhi(u4.z);
    q[i*8+6] = bflo(u4.w); q[i*8+7] = bfhi(u4.w);
  }
  __syncthreads();

  // ---- scores -> p = exp(s-8) directly (exp once here, not 4x in PV) ----
  const float scale = 0.17677669529663687f;  // 32^-0.5
  const int nb0    = (dg == 0) ? 0 : dg * 12 + 1;
  const int ncount = (dg == 0) ? 13 : 12;
  float sreg[13];
#pragma unroll
  for (int j = 0; j < 13; ++j) {
    if (j < ncount) {
      int nb = nb0 + j;
      int dy = nb / 7 - 3;
      int dx = nb % 7 - 3;
      int ry = r + dy + 3;
      int nx = x + dx;
      int xx = min(max(nx, 0), 63);
      int ny = y0 + r + dy;
      bool valid = (ny >= 0) && (ny <= 63) && (nx >= 0) && (nx <= 63);
      const unsigned int* kb = &smem[(ry * 64 + xx) * 20];
      float acc = 0.f;
#pragma unroll
      for (int c = 0; c < 4; ++c) {
        uint4 u4 = *(const uint4*)&kb[c * 4];
        acc += q[c*8+0] * bflo(u4.x) + q[c*8+1] * bfhi(u4.x);
        acc += q[c*8+2] * bflo(u4.y) + q[c*8+3] * bfhi(u4.y);
        acc += q[c*8+4] * bflo(u4.z) + q[c*8+5] * bfhi(u4.z);
        acc += q[c*8+6] * bflo(u4.w) + q[c*8+7] * bfhi(u4.w);
      }
      sreg[j] = valid ? __expf(acc * scale - 8.0f) : 0.0f;   // |s|<<8 -> overflow-safe
    }
  }
  __syncthreads();                   // all K reads done before sS overlay
#pragma unroll
  for (int j = 0; j < 13; ++j)
    if (j < ncount) sS[(nb0 + j) * 128 + px] = sreg[j];
  __syncthreads();

  // ---- PV: p from sS (1 b32) + V (1 b128) per neighbor ----
  float o[8] = {0.f, 0.f, 0.f, 0.f, 0.f, 0.f, 0.f, 0.f};
  float sum = 0.f;
#pragma unroll
  for (int nb = 0; nb < 49; ++nb) {
    float p = sS[nb * 128 + px];
    sum += p;
    int ry = r + nb / 7;                          // nb static
    int xx = min(max(x + nb % 7 - 3, 0), 63);
    uint4 u4 = *(const uint4*)&smem[10240 + (ry * 64 + xx) * 20 + dg * 4];
    o[0] += p * bflo(u4.x); o[1] += p * bfhi(u4.x);
    o[2] += p * bflo(u4.y); o[3] += p * bfhi(u4.y);
    o[4] += p * bflo(u4.z); o[5] += p * bfhi(u4.z);
    o[6] += p * bflo(u4.w); o[7] += p * bfhi(u4.w);
  }
  float inv = 1.0f / sum;
  unsigned int pk[4];
#pragma unroll
  for (int j = 0; j < 4; ++j)
    pk[j] = f2bf(o[2*j] * inv) | (f2bf(o[2*j+1] * inv) << 16);
  *(uint4*)&ATT[(size_t)Pq * CDIM + h * HD + dg * 8] = make_uint4(pk[0], pk[1], pk[2], pk[3]);
}

// ================= tail: wo-conv + z-res + ffn-rmsnorm + ffn1 + gelu + ffn2 + res ======
// Block: 32 px, 256 thr, grid 256. ZNEW & FN live only in LDS.
__global__ __launch_bounds__(256) void tail(
    const ushort* __restrict__ ATT, const ushort* __restrict__ WB,
    const float* __restrict__ bo, const float* __restrict__ z,
    const float* __restrict__ wfn, const float* __restrict__ b1,
    const float* __restrict__ b2, float* __restrict__ out) {
  __shared__ __align__(16) float  zlds[32][132];    // fp32 ZNEW tile
  __shared__ __align__(16) ushort fn_s[32 * 128];   // bf16 FN, XOR-swizzled
  __shared__ __align__(16) ushort hid_s[32 * 256];  // bf16 hidden, XOR-swizzled
  __shared__ float sums[32][17];
  __shared__ float sinv[32];
  const ushort* Wo = WB + 49152;
  const ushort* W1 = WB + 65536;
  const ushort* W2 = WB + 98304;
  const int t = threadIdx.x, w = t >> 6, l = t & 63, lr = l & 15, lk = l >> 4;
  const int pblk = blockIdx.x * 32;
  const int m0 = w * 32;

  // ---- phase A: wo GEMM (K=128), 4 waves x (32 out x 32 px) ----
  {
    const ushort* A0 = Wo + (size_t)(m0 + lr) * 128 + lk * 8;
    const ushort* A1 = A0 + 16 * 128;
    const ushort* B0 = ATT + (size_t)(pblk + lr) * 128 + lk * 8;
    const ushort* B1 = B0 + 16 * 128;
    f32x4 acc[2][2] = {};
#pragma unroll
    for (int k0 = 0; k0 < 128; k0 += 32) {
      bf16x8 a0 = *(const bf16x8*)(A0 + k0);
      bf16x8 a1 = *(const bf16x8*)(A1 + k0);
      bf16x8 b0 = *(const bf16x8*)(B0 + k0);
      bf16x8 b1 = *(const bf16x8*)(B1 + k0);
      acc[0][0] = __builtin_amdgcn_mfma_f32_16x16x32_bf16(a0, b0, acc[0][0], 0, 0, 0);
      acc[0][1] = __builtin_amdgcn_mfma_f32_16x16x32_bf16(a0, b1, acc[0][1], 0, 0, 0);
      acc[1][0] = __builtin_amdgcn_mfma_f32_16x16x32_bf16(a1, b0, acc[1][0], 0, 0, 0);
      acc[1][1] = __builtin_amdgcn_mfma_f32_16x16x32_bf16(a1, b1, acc[1][1], 0, 0, 0);
    }
#pragma unroll
    for (int nf = 0; nf < 2; ++nf) {
      int px = nf * 16 + lr;
      int P  = pblk + px;
      int b_ = P >> 12, p = P & 4095;
      float ss = 0.f;
#pragma unroll
      for (int mf = 0; mf < 2; ++mf) {
        int row0 = m0 + mf * 16 + lk * 4;
        f32x4 bv = *(const f32x4*)&bo[row0];
        f32x4 rr;
#pragma unroll
        for (int j = 0; j < 4; ++j) {
          size_t gi = ((size_t)(b_ * CDIM + row0 + j)) * HW + p;
          float u = acc[mf][nf][j] + bv[j] + z[gi];
          rr[j] = u;
          ss += u * u;
        }
        *(f32x4*)&zlds[px][row0] = rr;
      }
      sums[px][w * 4 + lk] = ss;
    }
  }
  __syncthreads();
  if (t < 32) {
    float tot = 0.f;
#pragma unroll
    for (int i = 0; i < 16; ++i) tot += sums[t][i];
    sinv[t] = rsqrtf(tot * (1.0f / CDIM) + 1e-8f);
  }
  __syncthreads();
  // ---- FN = rmsnorm(ZNEW)*wfn -> fn_s ----
#pragma unroll
  for (int nf = 0; nf < 2; ++nf) {
    int px = nf * 16 + lr;
    float inv = sinv[px];
#pragma unroll
    for (int mf = 0; mf < 2; ++mf) {
      int row0 = m0 + mf * 16 + lk * 4;
      f32x4 uu = *(const f32x4*)&zlds[px][row0];
      f32x4 wf = *(const f32x4*)&wfn[row0];
      uint2 pk;
      pk.x = f2bf(uu[0] * inv * wf[0]) | (f2bf(uu[1] * inv * wf[1]) << 16);
      pk.y = f2bf(uu[2] * inv * wf[2]) | (f2bf(uu[3] * inv * wf[3]) << 16);
      int idx = (px * 128 + row0) ^ ((px & 7) << 3);
      *(uint2*)&fn_s[idx] = pk;
    }
  }
  __syncthreads();
  // ---- phase B: ffn1 (K=128), 4 waves x (64 hid x 32 px); gelu -> hid_s ----
  {
    const int hm0 = w * 64;
    const ushort* A0 = W1 + (size_t)(hm0 + lr) * 128 + lk * 8;
    f32x4 acc1[4][2] = {};
#pragma unroll
    for (int k0 = 0; k0 < 128; k0 += 32) {
      bf16x8 a[4], b[2];
#pragma unroll
      for (int mf = 0; mf < 4; ++mf) a[mf] = *(const bf16x8*)(A0 + mf * 16 * 128 + k0);
#pragma unroll
      for (int nf = 0; nf < 2; ++nf) {
        int px = nf * 16 + lr;
        b[nf] = *(const bf16x8*)&fn_s[(px * 128 + k0 + lk * 8) ^ ((px & 7) << 3)];
      }
#pragma unroll
      for (int mf = 0; mf < 4; ++mf)
#pragma unroll
        for (int nf = 0; nf < 2; ++nf)
          acc1[mf][nf] = __builtin_amdgcn_mfma_f32_16x16x32_bf16(a[mf], b[nf], acc1[mf][nf], 0, 0, 0);
    }
#pragma unroll
    for (int mf = 0; mf < 4; ++mf) {
      int ch0 = hm0 + mf * 16 + lk * 4;
      f32x4 bv = *(const f32x4*)&b1[ch0];
#pragma unroll
      for (int nf = 0; nf < 2; ++nf) {
        int px = nf * 16 + lr;
        float v0 = gelu_f(acc1[mf][nf][0] + bv[0]);
        float v1 = gelu_f(acc1[mf][nf][1] + bv[1]);
        float v2 = gelu_f(acc1[mf][nf][2] + bv[2]);
        float v3 = gelu_f(acc1[mf][nf][3] + bv[3]);
        uint2 pk;
        pk.x = f2bf(v0) | (f2bf(v1) << 16);
        pk.y = f2bf(v2) | (f2bf(v3) << 16);
        int idx = (px * 256 + ch0) ^ ((px & 7) << 3);
        *(uint2*)&hid_s[idx] = pk;
      }
    }
  }
  __syncthreads();
  // ---- phase C: ffn2 (K=256), 4 waves x (32 out x 32 px); +b2 +ZNEW -> out ----
  {
    const ushort* C0 = W2 + (size_t)(m0 + lr) * 256 + lk * 8;
    f32x4 acc2[2][2] = {};
#pragma unroll
    for (int k0 = 0; k0 < 256; k0 += 32) {
      bf16x8 a0 = *(const bf16x8*)(C0 + k0);
      bf16x8 a1 = *(const bf16x8*)(C0 + 16 * 256 + k0);
      bf16x8 b[2];
#pragma unroll
      for (int nf = 0; nf < 2; ++nf) {
        int px = nf * 16 + lr;
        b[nf] = *(const bf16x8*)&hid_s[(px * 256 + k0 + lk * 8) ^ ((px & 7) << 3)];
      }
      acc2[0][0] = __builtin_amdgcn_mfma_f32_16x16x32_bf16(a0, b[0], acc2[0][0], 0, 0, 0);
      acc2[0][1] = __builtin_amdgcn_mfma_f32_16x16x32_bf16(a0, b[1], acc2[0][1], 0, 0, 0);
      acc2[1][0] = __builtin_amdgcn_mfma_f32_16x16x32_bf16(a1, b[0], acc2[1][0], 0, 0, 0);
      acc2[1][1] = __builtin_amdgcn_mfma_f32_16x16x32_bf16(a1, b[1], acc2[1][1], 0, 0, 0);
    }
#pragma unroll
    for (int mf = 0; mf < 2; ++mf) {
      int row0 = m0 + mf * 16 + lk * 4;
      f32x4 bv = *(const f32x4*)&b2[row0];
#pragma unroll
      for (int nf = 0; nf < 2; ++nf) {
        int px = nf * 16 + lr;
        int P  = pblk + px;
        int b_ = P >> 12, p = P & 4095;
        f32x4 zz = *(const f32x4*)&zlds[px][row0];
#pragma unroll
        for (int j = 0; j < 4; ++j) {
          size_t gi = ((size_t)(b_ * CDIM + row0 + j)) * HW + p;
          out[gi] = acc2[mf][nf][j] + bv[j] + zz[j];
        }
      }
    }
  }
}

// ================= launch =================
extern "C" void kernel_launch(void* const* d_in, const int* in_sizes, int n_in,
                              void* d_out, int out_size, void* d_ws, size_t ws_size,
                              hipStream_t stream) {
  const float* z   = (const float*)d_in[0];
  const float* h   = (const float*)d_in[1];
  const float* wzn = (const float*)d_in[2];
  const float* whn = (const float*)d_in[3];
  const float* wq  = (const float*)d_in[4];
  const float* bq  = (const float*)d_in[5];
  const float* wk  = (const float*)d_in[6];
  const float* bk  = (const float*)d_in[7];
  const float* wv  = (const float*)d_in[8];
  const float* bv  = (const float*)d_in[9];
  const float* wo  = (const float*)d_in[10];
  const float* bo  = (const float*)d_in[11];
  const float* wfn = (const float*)d_in[12];
  const float* w1  = (const float*)d_in[13];
  const float* b1  = (const float*)d_in[14];
  const float* w2  = (const float*)d_in[15];
  const float* b2  = (const float*)d_in[16];
  float* out = (float*)d_out;

  const size_t U = 1048576;                  // one [8192][128] bf16 tensor (ushorts)
  ushort* Qb  = (ushort*)d_ws;
  ushort* Kb  = Qb + U;
  ushort* Vb  = Kb + U;
  ushort* ATT = Vb + U;
  ushort* WB  = ATT + U;                     // 131072 ushorts (wo/w1/w2 at +49152)

  head<<<dim3(128, 4), 256, 0, stream>>>(z, h, wzn, whn, wq, bq, wk, bk, wv, bv,
                                         wo, w1, w2, WB, Qb, Kb, Vb);
  nattn<<<dim3(32, HEADS, 2), 512, 0, stream>>>(Qb, Kb, Vb, ATT);
  tail<<<dim3(256), 256, 0, stream>>>(ATT, WB, bo, z, wfn, b1, b2, out);
}